// Round 20
// baseline (230.637 us; speedup 1.0000x reference)
//
#include <hip/hip_runtime.h>
#include <hip/hip_bf16.h>
#include <math.h>

typedef _Float16 half8 __attribute__((ext_vector_type(8)));
typedef __fp16 fp16x2 __attribute__((ext_vector_type(2)));
typedef float f32x4 __attribute__((ext_vector_type(4)));
typedef float f32x16 __attribute__((ext_vector_type(16)));

#define D 128
#define SQ 8192
#define SKV 8192
#define BQ 256    // q-rows per block (8 waves x 32)
#define BKV 64
#define LOG2E 1.4426950408889634f
#define DEFER_THR 11.5417f   // 8 * log2(e); P <= 2^11.54 ~ 2981 < f16 max

__device__ __forceinline__ float bf2f(ushort h) {
  union { unsigned u; float f; } v; v.u = ((unsigned)h) << 16;
  return v.f;
}
__device__ __forceinline__ unsigned cvtpk_bf(float a, float b) {
  unsigned r;
  asm("v_cvt_pk_bf16_f32 %0, %1, %2" : "=v"(r) : "v"(a), "v"(b));
  return r;
}
__device__ __forceinline__ unsigned cvtpk_h(float a, float b) {
  union { fp16x2 h; unsigned u; } r;
  r.h = __builtin_amdgcn_cvt_pkrtz(a, b);
  return r.u;
}
__device__ __forceinline__ float fexp2(float x) {
  float r;
  asm("v_exp_f32 %0, %1" : "=v"(r) : "v"(x));
  return r;
}
__device__ __forceinline__ void pl32swap(unsigned& a, unsigned& b) {
  asm("v_permlane32_swap_b32 %0, %1" : "+v"(a), "+v"(b));
}

// Merged, vectorized prep (1024 blocks) — unchanged from r16 (validated)
__global__ void prep_all(const float* __restrict__ q, const float* __restrict__ k,
                         const float* __restrict__ v,
                         _Float16* __restrict__ QT, _Float16* __restrict__ PK,
                         _Float16* __restrict__ PV) {
  int b = blockIdx.x;
  int t = threadIdx.x;
  if (b < 512) {
    const bool isQ = (b < 256);
    const float* src = isQ ? q : k;
    const float scl = isQ ? LOG2E : 1.0f;
    int s0 = (isQ ? b : b - 256) * 32;
    __shared__ float lds[128][33];
    int dr = t >> 5, l = t & 31;
#pragma unroll
    for (int j = 0; j < 16; ++j) {
      int dd = dr * 16 + j;
      lds[dd][l] = src[(size_t)dd * SQ + s0 + l];
    }
    __syncthreads();
#pragma unroll
    for (int i = 0; i < 2; ++i) {
      int cid = t + i * 256;        // 0..511
      int c = cid >> 5, sl = cid & 31;
      half8 hv;
#pragma unroll
      for (int e = 0; e < 8; ++e) hv[e] = (_Float16)(lds[c * 8 + e][sl] * scl);
      if (isQ) {
        *(half8*)(QT + (size_t)(s0 + sl) * D + c * 8) = hv;
      } else {
        int srow = s0 + sl;
        size_t elem = (size_t)((srow >> 5) * 8 + (c >> 1)) * 512 +
                      ((c & 1) * 32 + (srow & 31)) * 8;
        *(half8*)(PK + elem) = hv;
      }
    }
  } else {
    int idx = (b - 512) * 256 + t;
    int i8 = idx * 8;
    float4 x0 = *(const float4*)(v + i8);
    float4 x1 = *(const float4*)(v + i8 + 4);
    int drow = i8 >> 13;          // / SKV
    int kv = i8 & (SKV - 1);
    size_t elem = (size_t)(kv >> 6) * 8192 +
                  (size_t)((drow >> 5) * 4 + ((kv >> 4) & 3)) * 512 +
                  (((kv >> 3) & 1) * 32 + (drow & 31)) * 8;
    half8 hv = { (_Float16)x0.x, (_Float16)x0.y, (_Float16)x0.z, (_Float16)x0.w,
                 (_Float16)x1.x, (_Float16)x1.y, (_Float16)x1.z, (_Float16)x1.w };
    *(half8*)(PV + elem) = hv;
  }
}

// r18 structure (best so far, byte-identical body): intra-wave 2-tile static
// pipeline, K double-buffered, V triple-buffered = exactly 80 KB LDS.
// NEW: nsplit=16 -> 512 blocks = TWO co-resident 8-wave blocks per CU
// (160KB LDS exact, 16 waves x 128 VGPR = full pool). Independent blocks
// drift out of phase -> cross-block MFMA/softmax overlap (4 waves/SIMD).
__global__ __launch_bounds__(512, 4)
void flash_fwd(const _Float16* __restrict__ QT, const _Float16* __restrict__ PK,
               const _Float16* __restrict__ PV,
               ushort* __restrict__ Opart, float* __restrict__ Mst,
               float* __restrict__ Lst, int splitLen) {
  __shared__ _Float16 Kl[2][BKV * D];   // 2 x 16 KB
  __shared__ _Float16 Vl[3][BKV * D];   // 3 x 16 KB

  const int tid = threadIdx.x;
  const int w = tid >> 6;        // 0..7
  const int lane = tid & 63;
  const int lc = lane & 31;
  const int hi = lane >> 5;
  const int qb = blockIdx.x;
  const int split = blockIdx.y;
  const int qrow = qb * BQ + w * 32 + lc;

  // Q B-frags (col = q = lc, k-dim = d), pre-scaled by log2e
  half8 qh[8];
#pragma unroll
  for (int ds = 0; ds < 8; ++ds)
    qh[ds] = *(const half8*)(QT + (size_t)qrow * D + ds * 16 + hi * 8);

  f32x16 Ot[4];
#pragma unroll
  for (int dt = 0; dt < 4; ++dt)
#pragma unroll
    for (int e = 0; e < 16; ++e) Ot[dt][e] = 0.f;
  float mrun = -INFINITY, lrun = 0.f;

  const int kvBase = split * splitLen;
  const int nsteps = splitLen / BKV;   // 8 at nsplit=16
  const int tB = kvBase / BKV;

  // staging: K tile -> Kl[KB], V tile -> Vl[VB]; 32 x 1KB chunks, 4 per wave
#define STAGE(KB, VB, T)                                                      \
  {                                                                           \
    _Pragma("unroll")                                                         \
    for (int j = 0; j < 4; ++j) {                                             \
      int cblk = w * 4 + j;                                                   \
      int cc = cblk & 15;                                                     \
      const _Float16* gp = ((cblk < 16) ? PK : PV) +                          \
                           (size_t)(T) * (BKV * D) + cc * 512 + lane * 8;     \
      _Float16* lp = ((cblk < 16) ? &Kl[KB][0] : &Vl[VB][0]) + cc * 512;      \
      __builtin_amdgcn_global_load_lds(                                       \
          (const __attribute__((address_space(1))) unsigned*)gp,              \
          (__attribute__((address_space(3))) unsigned*)lp, 16, 0, 0);         \
    }                                                                         \
  }

  // QK burst: 16 ds_read + 16 MFMA (two independent 8-chains) into s0/s1
  auto QKX = [&](int kb2, f32x16& s0, f32x16& s1) {
    const _Float16* kb = &Kl[kb2][0] + lane * 8;
#pragma unroll
    for (int e = 0; e < 16; ++e) { s0[e] = 0.f; s1[e] = 0.f; }
    __builtin_amdgcn_s_setprio(1);
#pragma unroll
    for (int ds = 0; ds < 8; ++ds) {
      half8 k0 = *(const half8*)(kb + ds * 512);
      half8 k1 = *(const half8*)(kb + (8 + ds) * 512);
      s0 = __builtin_amdgcn_mfma_f32_32x32x16_f16(k0, qh[ds], s0, 0, 0, 0);
      s1 = __builtin_amdgcn_mfma_f32_32x32x16_f16(k1, qh[ds], s1, 0, 0, 0);
    }
    __builtin_amdgcn_s_setprio(0);
  };

  // softmax (exp2 domain) + pack + PV for S in s0/s1, V in Vl[vb3]
  auto SMPV = [&](f32x16& s0, f32x16& s1, int vb3) {
    float t8[8];
#pragma unroll
    for (int e = 0; e < 8; ++e)
      t8[e] = fmaxf(fmaxf(s0[e], s0[e + 8]), fmaxf(s1[e], s1[e + 8]));
    float mx = fmaxf(fmaxf(fmaxf(t8[0], t8[4]), fmaxf(t8[1], t8[5])),
                     fmaxf(fmaxf(t8[2], t8[6]), fmaxf(t8[3], t8[7])));
    mx = fmaxf(mx, __shfl_xor(mx, 32));
    if (!__all(mx - mrun <= DEFER_THR)) {     // defer-max (T13)
      float mn = fmaxf(mrun, mx);
      float sc = fexp2(mrun - mn);            // first iter: exp2(-inf)=0
      mrun = mn;
      lrun *= sc;
#pragma unroll
      for (int dt = 0; dt < 4; ++dt)
#pragma unroll
        for (int e = 0; e < 16; ++e) Ot[dt][e] *= sc;
    }
#pragma unroll
    for (int e = 0; e < 16; ++e) {
      s0[e] = fexp2(s0[e] - mrun);
      s1[e] = fexp2(s1[e] - mrun);
    }
    float a8[8];
#pragma unroll
    for (int e = 0; e < 8; ++e) a8[e] = (s0[e] + s0[e + 8]) + (s1[e] + s1[e + 8]);
    float lsum = ((a8[0] + a8[4]) + (a8[1] + a8[5])) +
                 ((a8[2] + a8[6]) + (a8[3] + a8[7]));
    lsum += __shfl_xor(lsum, 32);
    lrun += lsum;

    unsigned pk[8];
    half8 pb[4];
    union { unsigned u[4]; half8 v; } pbu;
#pragma unroll
    for (int j = 0; j < 8; ++j) pk[j] = cvtpk_h(s0[2 * j], s0[2 * j + 1]);
    pl32swap(pk[0], pk[2]); pl32swap(pk[1], pk[3]);
    pl32swap(pk[4], pk[6]); pl32swap(pk[5], pk[7]);
    pbu.u[0] = pk[0]; pbu.u[1] = pk[1]; pbu.u[2] = pk[2]; pbu.u[3] = pk[3]; pb[0] = pbu.v;
    pbu.u[0] = pk[4]; pbu.u[1] = pk[5]; pbu.u[2] = pk[6]; pbu.u[3] = pk[7]; pb[1] = pbu.v;
#pragma unroll
    for (int j = 0; j < 8; ++j) pk[j] = cvtpk_h(s1[2 * j], s1[2 * j + 1]);
    pl32swap(pk[0], pk[2]); pl32swap(pk[1], pk[3]);
    pl32swap(pk[4], pk[6]); pl32swap(pk[5], pk[7]);
    pbu.u[0] = pk[0]; pbu.u[1] = pk[1]; pbu.u[2] = pk[2]; pbu.u[3] = pk[3]; pb[2] = pbu.v;
    pbu.u[0] = pk[4]; pbu.u[1] = pk[5]; pbu.u[2] = pk[6]; pbu.u[3] = pk[7]; pb[3] = pbu.v;

    const _Float16* vb = &Vl[vb3][0] + lane * 8;
    __builtin_amdgcn_s_setprio(1);
#pragma unroll
    for (int dt = 0; dt < 4; ++dt) {
      half8 v0 = *(const half8*)(vb + (dt * 4 + 0) * 512);
      half8 v1 = *(const half8*)(vb + (dt * 4 + 1) * 512);
      half8 v2 = *(const half8*)(vb + (dt * 4 + 2) * 512);
      half8 v3 = *(const half8*)(vb + (dt * 4 + 3) * 512);
      Ot[dt] = __builtin_amdgcn_mfma_f32_32x32x16_f16(v0, pb[0], Ot[dt], 0, 0, 0);
      Ot[dt] = __builtin_amdgcn_mfma_f32_32x32x16_f16(v1, pb[1], Ot[dt], 0, 0, 0);
      Ot[dt] = __builtin_amdgcn_mfma_f32_32x32x16_f16(v2, pb[2], Ot[dt], 0, 0, 0);
      Ot[dt] = __builtin_amdgcn_mfma_f32_32x32x16_f16(v3, pb[3], Ot[dt], 0, 0, 0);
    }
    __builtin_amdgcn_s_setprio(0);
  };

  f32x16 sA0, sA1, sB0, sB1;

  // ---- prologue: tile 0 ----
  STAGE(0, 0, tB);
  __syncthreads();
  if (nsteps > 1) STAGE(1, 1, tB + 1);
  QKX(0, sA0, sA1);
  __syncthreads();          // tile 1 landed

  // ---- main: phase p = {QK(tile p), SMPV(tile p-1)}, unrolled by 2 ----
  int p = 1;
  for (; p + 1 < nsteps; p += 2) {
    // phase p (odd): reads K1,V[(p-1)%3]; writes K0,V[(p+1)%3]
    STAGE(0, (p + 1) % 3, tB + p + 1);
    QKX(1, sB0, sB1);
    SMPV(sA0, sA1, (p - 1) % 3);
    __syncthreads();
    // phase p+1 (even): reads K0,V[p%3]; writes K1,V[(p+2)%3]
    if (p + 2 < nsteps) STAGE(1, (p + 2) % 3, tB + p + 2);
    QKX(0, sA0, sA1);
    SMPV(sB0, sB1, p % 3);
    __syncthreads();
  }
  if (p < nsteps) {
    // last odd phase (nsteps even): no staging left
    QKX(1, sB0, sB1);
    SMPV(sA0, sA1, (p - 1) % 3);
    SMPV(sB0, sB1, p % 3);
  } else {
    // nsteps odd: last tile is in sA
    SMPV(sA0, sA1, (nsteps - 1) % 3);
  }

  // ---- epilogue: bf16 partials; d = dt*32 + rg*8 + hi*4 + e ----
  ushort* Op = Opart + (size_t)split * SQ * D + (size_t)qrow * D;
#pragma unroll
  for (int dt = 0; dt < 4; ++dt) {
#pragma unroll
    for (int rg = 0; rg < 4; ++rg) {
      uint2 o2;
      o2.x = cvtpk_bf(Ot[dt][4 * rg + 0], Ot[dt][4 * rg + 1]);
      o2.y = cvtpk_bf(Ot[dt][4 * rg + 2], Ot[dt][4 * rg + 3]);
      *(uint2*)(Op + dt * 32 + rg * 8 + hi * 4) = o2;
    }
  }
  if (hi == 0) {
    Mst[split * SQ + qrow] = mrun;   // log2-domain
    Lst[split * SQ + qrow] = lrun;
  }
}

__global__ void combine(const ushort* __restrict__ Opart, const float* __restrict__ Mst,
                        const float* __restrict__ Lst, float* __restrict__ out, int nsplit) {
  int t4 = (blockIdx.x * 256 + threadIdx.x) * 4;
  int qi = t4 >> 7;
  float M = -INFINITY;
  for (int s = 0; s < nsplit; ++s) M = fmaxf(M, Mst[s * SQ + qi]);
  float n0 = 0.f, n1 = 0.f, n2 = 0.f, n3 = 0.f, den = 0.f;
  for (int s = 0; s < nsplit; ++s) {
    float wgt = fexp2(Mst[s * SQ + qi] - M);
    den += wgt * Lst[s * SQ + qi];
    ushort4 u = *(const ushort4*)(Opart + (size_t)s * SQ * D + t4);
    n0 += wgt * bf2f(u.x); n1 += wgt * bf2f(u.y);
    n2 += wgt * bf2f(u.z); n3 += wgt * bf2f(u.w);
  }
  float inv = 1.0f / den;
  float4 o = { n0 * inv, n1 * inv, n2 * inv, n3 * inv };
  *(float4*)(out + t4) = o;
}

extern "C" void kernel_launch(void* const* d_in, const int* in_sizes, int n_in,
                              void* d_out, int out_size, void* d_ws, size_t ws_size,
                              hipStream_t stream) {
  const float* q = (const float*)d_in[0];
  const float* k = (const float*)d_in[1];
  const float* v = (const float*)d_in[2];
  float* out = (float*)d_out;

  char* ws = (char*)d_ws;
  const size_t mat = (size_t)SQ * D * 2;   // 2 MB per f16 matrix
  _Float16* QT = (_Float16*)(ws);
  _Float16* PK = (_Float16*)(ws + mat);
  _Float16* PV = (_Float16*)(ws + 2 * mat);
  char* rest = ws + 3 * mat;

  const size_t opartSz = (size_t)SQ * D * 2;  // bf16 partials: 2 MB per split
  const size_t statSz  = (size_t)SQ * 4;
  int nsplit = 16;   // grid 32 x 16 = 512 blocks = 2 co-resident 8-wave/CU
  while (nsplit > 1 &&
         3 * mat + (size_t)nsplit * (opartSz + 2 * statSz) > ws_size) nsplit >>= 1;

  ushort* Opart = (ushort*)rest;
  float* Mst = (float*)(rest + (size_t)nsplit * opartSz);
  float* Lst = (float*)(rest + (size_t)nsplit * opartSz + (size_t)nsplit * statSz);

  prep_all<<<1024, 256, 0, stream>>>(q, k, v, QT, PK, PV);
  flash_fwd<<<dim3(SQ / BQ, nsplit), 512, 0, stream>>>(QT, PK, PV,
                                                       Opart, Mst, Lst, SKV / nsplit);
  combine<<<(SQ * D) / (256 * 4), 256, 0, stream>>>(Opart, Mst, Lst, out, nsplit);
}

// Round 21
// 70.656 us; speedup vs baseline: 3.2642x; 3.2642x over previous
//
#include <hip/hip_runtime.h>
#include <hip/hip_bf16.h>
#include <math.h>

typedef _Float16 half8 __attribute__((ext_vector_type(8)));
typedef __fp16 fp16x2 __attribute__((ext_vector_type(2)));
typedef float f32x4 __attribute__((ext_vector_type(4)));
typedef float f32x16 __attribute__((ext_vector_type(16)));

#define D 128
#define SQ 8192
#define SKV 8192
#define BQ 256    // q-rows per block (8 waves x 32)
#define BKV 64
#define LOG2E 1.4426950408889634f
#define DEFER_THR 11.5417f   // 8 * log2(e); P <= 2^11.54 ~ 2981 < f16 max

__device__ __forceinline__ float bf2f(ushort h) {
  union { unsigned u; float f; } v; v.u = ((unsigned)h) << 16;
  return v.f;
}
__device__ __forceinline__ unsigned cvtpk_bf(float a, float b) {
  unsigned r;
  asm("v_cvt_pk_bf16_f32 %0, %1, %2" : "=v"(r) : "v"(a), "v"(b));
  return r;
}
__device__ __forceinline__ unsigned cvtpk_h(float a, float b) {
  union { fp16x2 h; unsigned u; } r;
  r.h = __builtin_amdgcn_cvt_pkrtz(a, b);
  return r.u;
}
__device__ __forceinline__ float fexp2(float x) {
  float r;
  asm("v_exp_f32 %0, %1" : "=v"(r) : "v"(x));
  return r;
}
__device__ __forceinline__ void pl32swap(unsigned& a, unsigned& b) {
  asm("v_permlane32_swap_b32 %0, %1" : "+v"(a), "+v"(b));
}

// Merged, vectorized prep (1024 blocks) — unchanged from r16 (validated)
__global__ void prep_all(const float* __restrict__ q, const float* __restrict__ k,
                         const float* __restrict__ v,
                         _Float16* __restrict__ QT, _Float16* __restrict__ PK,
                         _Float16* __restrict__ PV) {
  int b = blockIdx.x;
  int t = threadIdx.x;
  if (b < 512) {
    const bool isQ = (b < 256);
    const float* src = isQ ? q : k;
    const float scl = isQ ? LOG2E : 1.0f;
    int s0 = (isQ ? b : b - 256) * 32;
    __shared__ float lds[128][33];
    int dr = t >> 5, l = t & 31;
#pragma unroll
    for (int j = 0; j < 16; ++j) {
      int dd = dr * 16 + j;
      lds[dd][l] = src[(size_t)dd * SQ + s0 + l];
    }
    __syncthreads();
#pragma unroll
    for (int i = 0; i < 2; ++i) {
      int cid = t + i * 256;        // 0..511
      int c = cid >> 5, sl = cid & 31;
      half8 hv;
#pragma unroll
      for (int e = 0; e < 8; ++e) hv[e] = (_Float16)(lds[c * 8 + e][sl] * scl);
      if (isQ) {
        *(half8*)(QT + (size_t)(s0 + sl) * D + c * 8) = hv;
      } else {
        int srow = s0 + sl;
        size_t elem = (size_t)((srow >> 5) * 8 + (c >> 1)) * 512 +
                      ((c & 1) * 32 + (srow & 31)) * 8;
        *(half8*)(PK + elem) = hv;
      }
    }
  } else {
    int idx = (b - 512) * 256 + t;
    int i8 = idx * 8;
    float4 x0 = *(const float4*)(v + i8);
    float4 x1 = *(const float4*)(v + i8 + 4);
    int drow = i8 >> 13;          // / SKV
    int kv = i8 & (SKV - 1);
    size_t elem = (size_t)(kv >> 6) * 8192 +
                  (size_t)((drow >> 5) * 4 + ((kv >> 4) & 3)) * 512 +
                  (((kv >> 3) & 1) * 32 + (drow & 31)) * 8;
    half8 hv = { (_Float16)x0.x, (_Float16)x0.y, (_Float16)x0.z, (_Float16)x0.w,
                 (_Float16)x1.x, (_Float16)x1.y, (_Float16)x1.z, (_Float16)x1.w };
    *(half8*)(PV + elem) = hv;
  }
}

// r18 structure and launch bounds EXACTLY (compiles to 128 VGPR, no spills).
// Only the grid changes: nsplit=16 -> 512 blocks. Two 8-wave blocks co-reside
// per CU by resource packing alone (80KB x 2 = 160KB LDS exact; 128 VGPR x 4
// waves/SIMD = 512 pool exact) -> independent blocks provide cross-block
// MFMA/softmax overlap without any allocator-visible change.
__global__ __launch_bounds__(512, 2)
void flash_fwd(const _Float16* __restrict__ QT, const _Float16* __restrict__ PK,
               const _Float16* __restrict__ PV,
               ushort* __restrict__ Opart, float* __restrict__ Mst,
               float* __restrict__ Lst, int splitLen) {
  __shared__ _Float16 Kl[2][BKV * D];   // 2 x 16 KB
  __shared__ _Float16 Vl[3][BKV * D];   // 3 x 16 KB

  const int tid = threadIdx.x;
  const int w = tid >> 6;        // 0..7
  const int lane = tid & 63;
  const int lc = lane & 31;
  const int hi = lane >> 5;
  const int qb = blockIdx.x;
  const int split = blockIdx.y;
  const int qrow = qb * BQ + w * 32 + lc;

  // Q B-frags (col = q = lc, k-dim = d), pre-scaled by log2e
  half8 qh[8];
#pragma unroll
  for (int ds = 0; ds < 8; ++ds)
    qh[ds] = *(const half8*)(QT + (size_t)qrow * D + ds * 16 + hi * 8);

  f32x16 Ot[4];
#pragma unroll
  for (int dt = 0; dt < 4; ++dt)
#pragma unroll
    for (int e = 0; e < 16; ++e) Ot[dt][e] = 0.f;
  float mrun = -INFINITY, lrun = 0.f;

  const int kvBase = split * splitLen;
  const int nsteps = splitLen / BKV;   // 8 at nsplit=16
  const int tB = kvBase / BKV;

  // staging: K tile -> Kl[KB], V tile -> Vl[VB]; 32 x 1KB chunks, 4 per wave
#define STAGE(KB, VB, T)                                                      \
  {                                                                           \
    _Pragma("unroll")                                                         \
    for (int j = 0; j < 4; ++j) {                                             \
      int cblk = w * 4 + j;                                                   \
      int cc = cblk & 15;                                                     \
      const _Float16* gp = ((cblk < 16) ? PK : PV) +                          \
                           (size_t)(T) * (BKV * D) + cc * 512 + lane * 8;     \
      _Float16* lp = ((cblk < 16) ? &Kl[KB][0] : &Vl[VB][0]) + cc * 512;      \
      __builtin_amdgcn_global_load_lds(                                       \
          (const __attribute__((address_space(1))) unsigned*)gp,              \
          (__attribute__((address_space(3))) unsigned*)lp, 16, 0, 0);         \
    }                                                                         \
  }

  // QK burst: 16 ds_read + 16 MFMA (two independent 8-chains) into s0/s1
  auto QKX = [&](int kb2, f32x16& s0, f32x16& s1) {
    const _Float16* kb = &Kl[kb2][0] + lane * 8;
#pragma unroll
    for (int e = 0; e < 16; ++e) { s0[e] = 0.f; s1[e] = 0.f; }
    __builtin_amdgcn_s_setprio(1);
#pragma unroll
    for (int ds = 0; ds < 8; ++ds) {
      half8 k0 = *(const half8*)(kb + ds * 512);
      half8 k1 = *(const half8*)(kb + (8 + ds) * 512);
      s0 = __builtin_amdgcn_mfma_f32_32x32x16_f16(k0, qh[ds], s0, 0, 0, 0);
      s1 = __builtin_amdgcn_mfma_f32_32x32x16_f16(k1, qh[ds], s1, 0, 0, 0);
    }
    __builtin_amdgcn_s_setprio(0);
  };

  // softmax (exp2 domain) + pack + PV for S in s0/s1, V in Vl[vb3]
  auto SMPV = [&](f32x16& s0, f32x16& s1, int vb3) {
    float t8[8];
#pragma unroll
    for (int e = 0; e < 8; ++e)
      t8[e] = fmaxf(fmaxf(s0[e], s0[e + 8]), fmaxf(s1[e], s1[e + 8]));
    float mx = fmaxf(fmaxf(fmaxf(t8[0], t8[4]), fmaxf(t8[1], t8[5])),
                     fmaxf(fmaxf(t8[2], t8[6]), fmaxf(t8[3], t8[7])));
    mx = fmaxf(mx, __shfl_xor(mx, 32));
    if (!__all(mx - mrun <= DEFER_THR)) {     // defer-max (T13)
      float mn = fmaxf(mrun, mx);
      float sc = fexp2(mrun - mn);            // first iter: exp2(-inf)=0
      mrun = mn;
      lrun *= sc;
#pragma unroll
      for (int dt = 0; dt < 4; ++dt)
#pragma unroll
        for (int e = 0; e < 16; ++e) Ot[dt][e] *= sc;
    }
#pragma unroll
    for (int e = 0; e < 16; ++e) {
      s0[e] = fexp2(s0[e] - mrun);
      s1[e] = fexp2(s1[e] - mrun);
    }
    float a8[8];
#pragma unroll
    for (int e = 0; e < 8; ++e) a8[e] = (s0[e] + s0[e + 8]) + (s1[e] + s1[e + 8]);
    float lsum = ((a8[0] + a8[4]) + (a8[1] + a8[5])) +
                 ((a8[2] + a8[6]) + (a8[3] + a8[7]));
    lsum += __shfl_xor(lsum, 32);
    lrun += lsum;

    unsigned pk[8];
    half8 pb[4];
    union { unsigned u[4]; half8 v; } pbu;
#pragma unroll
    for (int j = 0; j < 8; ++j) pk[j] = cvtpk_h(s0[2 * j], s0[2 * j + 1]);
    pl32swap(pk[0], pk[2]); pl32swap(pk[1], pk[3]);
    pl32swap(pk[4], pk[6]); pl32swap(pk[5], pk[7]);
    pbu.u[0] = pk[0]; pbu.u[1] = pk[1]; pbu.u[2] = pk[2]; pbu.u[3] = pk[3]; pb[0] = pbu.v;
    pbu.u[0] = pk[4]; pbu.u[1] = pk[5]; pbu.u[2] = pk[6]; pbu.u[3] = pk[7]; pb[1] = pbu.v;
#pragma unroll
    for (int j = 0; j < 8; ++j) pk[j] = cvtpk_h(s1[2 * j], s1[2 * j + 1]);
    pl32swap(pk[0], pk[2]); pl32swap(pk[1], pk[3]);
    pl32swap(pk[4], pk[6]); pl32swap(pk[5], pk[7]);
    pbu.u[0] = pk[0]; pbu.u[1] = pk[1]; pbu.u[2] = pk[2]; pbu.u[3] = pk[3]; pb[2] = pbu.v;
    pbu.u[0] = pk[4]; pbu.u[1] = pk[5]; pbu.u[2] = pk[6]; pbu.u[3] = pk[7]; pb[3] = pbu.v;

    const _Float16* vb = &Vl[vb3][0] + lane * 8;
    __builtin_amdgcn_s_setprio(1);
#pragma unroll
    for (int dt = 0; dt < 4; ++dt) {
      half8 v0 = *(const half8*)(vb + (dt * 4 + 0) * 512);
      half8 v1 = *(const half8*)(vb + (dt * 4 + 1) * 512);
      half8 v2 = *(const half8*)(vb + (dt * 4 + 2) * 512);
      half8 v3 = *(const half8*)(vb + (dt * 4 + 3) * 512);
      Ot[dt] = __builtin_amdgcn_mfma_f32_32x32x16_f16(v0, pb[0], Ot[dt], 0, 0, 0);
      Ot[dt] = __builtin_amdgcn_mfma_f32_32x32x16_f16(v1, pb[1], Ot[dt], 0, 0, 0);
      Ot[dt] = __builtin_amdgcn_mfma_f32_32x32x16_f16(v2, pb[2], Ot[dt], 0, 0, 0);
      Ot[dt] = __builtin_amdgcn_mfma_f32_32x32x16_f16(v3, pb[3], Ot[dt], 0, 0, 0);
    }
    __builtin_amdgcn_s_setprio(0);
  };

  f32x16 sA0, sA1, sB0, sB1;

  // ---- prologue: tile 0 ----
  STAGE(0, 0, tB);
  __syncthreads();
  if (nsteps > 1) STAGE(1, 1, tB + 1);
  QKX(0, sA0, sA1);
  __syncthreads();          // tile 1 landed

  // ---- main: phase p = {QK(tile p), SMPV(tile p-1)}, unrolled by 2 ----
  int p = 1;
  for (; p + 1 < nsteps; p += 2) {
    // phase p (odd): reads K1,V[(p-1)%3]; writes K0,V[(p+1)%3]
    STAGE(0, (p + 1) % 3, tB + p + 1);
    QKX(1, sB0, sB1);
    SMPV(sA0, sA1, (p - 1) % 3);
    __syncthreads();
    // phase p+1 (even): reads K0,V[p%3]; writes K1,V[(p+2)%3]
    if (p + 2 < nsteps) STAGE(1, (p + 2) % 3, tB + p + 2);
    QKX(0, sA0, sA1);
    SMPV(sB0, sB1, p % 3);
    __syncthreads();
  }
  if (p < nsteps) {
    // last odd phase (nsteps even): no staging left
    QKX(1, sB0, sB1);
    SMPV(sA0, sA1, (p - 1) % 3);
    SMPV(sB0, sB1, p % 3);
  } else {
    // nsteps odd: last tile is in sA
    SMPV(sA0, sA1, (nsteps - 1) % 3);
  }

  // ---- epilogue: bf16 partials; d = dt*32 + rg*8 + hi*4 + e ----
  ushort* Op = Opart + (size_t)split * SQ * D + (size_t)qrow * D;
#pragma unroll
  for (int dt = 0; dt < 4; ++dt) {
#pragma unroll
    for (int rg = 0; rg < 4; ++rg) {
      uint2 o2;
      o2.x = cvtpk_bf(Ot[dt][4 * rg + 0], Ot[dt][4 * rg + 1]);
      o2.y = cvtpk_bf(Ot[dt][4 * rg + 2], Ot[dt][4 * rg + 3]);
      *(uint2*)(Op + dt * 32 + rg * 8 + hi * 4) = o2;
    }
  }
  if (hi == 0) {
    Mst[split * SQ + qrow] = mrun;   // log2-domain
    Lst[split * SQ + qrow] = lrun;
  }
}

__global__ void combine(const ushort* __restrict__ Opart, const float* __restrict__ Mst,
                        const float* __restrict__ Lst, float* __restrict__ out, int nsplit) {
  int t4 = (blockIdx.x * 256 + threadIdx.x) * 4;
  int qi = t4 >> 7;
  float M = -INFINITY;
  for (int s = 0; s < nsplit; ++s) M = fmaxf(M, Mst[s * SQ + qi]);
  float n0 = 0.f, n1 = 0.f, n2 = 0.f, n3 = 0.f, den = 0.f;
  for (int s = 0; s < nsplit; ++s) {
    float wgt = fexp2(Mst[s * SQ + qi] - M);
    den += wgt * Lst[s * SQ + qi];
    ushort4 u = *(const ushort4*)(Opart + (size_t)s * SQ * D + t4);
    n0 += wgt * bf2f(u.x); n1 += wgt * bf2f(u.y);
    n2 += wgt * bf2f(u.z); n3 += wgt * bf2f(u.w);
  }
  float inv = 1.0f / den;
  float4 o = { n0 * inv, n1 * inv, n2 * inv, n3 * inv };
  *(float4*)(out + t4) = o;
}

extern "C" void kernel_launch(void* const* d_in, const int* in_sizes, int n_in,
                              void* d_out, int out_size, void* d_ws, size_t ws_size,
                              hipStream_t stream) {
  const float* q = (const float*)d_in[0];
  const float* k = (const float*)d_in[1];
  const float* v = (const float*)d_in[2];
  float* out = (float*)d_out;

  char* ws = (char*)d_ws;
  const size_t mat = (size_t)SQ * D * 2;   // 2 MB per f16 matrix
  _Float16* QT = (_Float16*)(ws);
  _Float16* PK = (_Float16*)(ws + mat);
  _Float16* PV = (_Float16*)(ws + 2 * mat);
  char* rest = ws + 3 * mat;

  const size_t opartSz = (size_t)SQ * D * 2;  // bf16 partials: 2 MB per split
  const size_t statSz  = (size_t)SQ * 4;
  int nsplit = 16;   // grid 32 x 16 = 512 blocks -> 2 co-resident 8-wave/CU
  while (nsplit > 1 &&
         3 * mat + (size_t)nsplit * (opartSz + 2 * statSz) > ws_size) nsplit >>= 1;

  ushort* Opart = (ushort*)rest;
  float* Mst = (float*)(rest + (size_t)nsplit * opartSz);
  float* Lst = (float*)(rest + (size_t)nsplit * opartSz + (size_t)nsplit * statSz);

  prep_all<<<1024, 256, 0, stream>>>(q, k, v, QT, PK, PV);
  flash_fwd<<<dim3(SQ / BQ, nsplit), 512, 0, stream>>>(QT, PK, PV,
                                                       Opart, Mst, Lst, SKV / nsplit);
  combine<<<(SQ * D) / (256 * 4), 256, 0, stream>>>(Opart, Mst, Lst, out, nsplit);
}

// Round 22
// 58.361 us; speedup vs baseline: 3.9519x; 1.2107x over previous
//
#include <hip/hip_runtime.h>
#include <hip/hip_bf16.h>
#include <math.h>

typedef _Float16 half8 __attribute__((ext_vector_type(8)));
typedef __fp16 fp16x2 __attribute__((ext_vector_type(2)));
typedef float f32x4 __attribute__((ext_vector_type(4)));
typedef float f32x16 __attribute__((ext_vector_type(16)));
typedef unsigned uint4v __attribute__((ext_vector_type(4)));

#define D 128
#define SQ 8192
#define SKV 8192
#define BQ 256    // q-rows per block (8 waves x 32)
#define BKV 64
#define LOG2E 1.4426950408889634f
#define DEFER_THR 11.5417f   // 8 * log2(e); P <= 2^11.54 ~ 2981 < f16 max

__device__ __forceinline__ float bf2f(ushort h) {
  union { unsigned u; float f; } v; v.u = ((unsigned)h) << 16;
  return v.f;
}
__device__ __forceinline__ unsigned cvtpk_bf(float a, float b) {
  unsigned r;
  asm("v_cvt_pk_bf16_f32 %0, %1, %2" : "=v"(r) : "v"(a), "v"(b));
  return r;
}
__device__ __forceinline__ unsigned cvtpk_h(float a, float b) {
  union { fp16x2 h; unsigned u; } r;
  r.h = __builtin_amdgcn_cvt_pkrtz(a, b);
  return r.u;
}
__device__ __forceinline__ float fexp2(float x) {
  float r;
  asm("v_exp_f32 %0, %1" : "=v"(r) : "v"(x));
  return r;
}
__device__ __forceinline__ void pl32swap(unsigned& a, unsigned& b) {
  asm("v_permlane32_swap_b32 %0, %1" : "+v"(a), "+v"(b));
}

// Merged, vectorized prep (1024 blocks) — unchanged from r16 (validated)
__global__ void prep_all(const float* __restrict__ q, const float* __restrict__ k,
                         const float* __restrict__ v,
                         _Float16* __restrict__ QT, _Float16* __restrict__ PK,
                         _Float16* __restrict__ PV) {
  int b = blockIdx.x;
  int t = threadIdx.x;
  if (b < 512) {
    const bool isQ = (b < 256);
    const float* src = isQ ? q : k;
    const float scl = isQ ? LOG2E : 1.0f;
    int s0 = (isQ ? b : b - 256) * 32;
    __shared__ float lds[128][33];
    int dr = t >> 5, l = t & 31;
#pragma unroll
    for (int j = 0; j < 16; ++j) {
      int dd = dr * 16 + j;
      lds[dd][l] = src[(size_t)dd * SQ + s0 + l];
    }
    __syncthreads();
#pragma unroll
    for (int i = 0; i < 2; ++i) {
      int cid = t + i * 256;        // 0..511
      int c = cid >> 5, sl = cid & 31;
      half8 hv;
#pragma unroll
      for (int e = 0; e < 8; ++e) hv[e] = (_Float16)(lds[c * 8 + e][sl] * scl);
      if (isQ) {
        *(half8*)(QT + (size_t)(s0 + sl) * D + c * 8) = hv;
      } else {
        int srow = s0 + sl;
        size_t elem = (size_t)((srow >> 5) * 8 + (c >> 1)) * 512 +
                      ((c & 1) * 32 + (srow & 31)) * 8;
        *(half8*)(PK + elem) = hv;
      }
    }
  } else {
    int idx = (b - 512) * 256 + t;
    int i8 = idx * 8;
    float4 x0 = *(const float4*)(v + i8);
    float4 x1 = *(const float4*)(v + i8 + 4);
    int drow = i8 >> 13;          // / SKV
    int kv = i8 & (SKV - 1);
    size_t elem = (size_t)(kv >> 6) * 8192 +
                  (size_t)((drow >> 5) * 4 + ((kv >> 4) & 3)) * 512 +
                  (((kv >> 3) & 1) * 32 + (drow & 31)) * 8;
    half8 hv = { (_Float16)x0.x, (_Float16)x0.y, (_Float16)x0.z, (_Float16)x0.w,
                 (_Float16)x1.x, (_Float16)x1.y, (_Float16)x1.z, (_Float16)x1.w };
    *(half8*)(PV + elem) = hv;
  }
}

// r18 flash (best measured: 47.7us, 128 VGPR, no spills): intra-wave 2-tile
// static pipeline, K double-buffered, V triple-buffered (80KB LDS), one
// barrier per tile, STAGE issued one tile ahead.
__global__ __launch_bounds__(512, 2)
void flash_fwd(const _Float16* __restrict__ QT, const _Float16* __restrict__ PK,
               const _Float16* __restrict__ PV,
               ushort* __restrict__ Opart, float* __restrict__ Mst,
               float* __restrict__ Lst, int splitLen) {
  __shared__ _Float16 Kl[2][BKV * D];   // 2 x 16 KB
  __shared__ _Float16 Vl[3][BKV * D];   // 3 x 16 KB

  const int tid = threadIdx.x;
  const int w = tid >> 6;        // 0..7
  const int lane = tid & 63;
  const int lc = lane & 31;
  const int hi = lane >> 5;
  const int qb = blockIdx.x;
  const int split = blockIdx.y;
  const int qrow = qb * BQ + w * 32 + lc;

  // Q B-frags (col = q = lc, k-dim = d), pre-scaled by log2e
  half8 qh[8];
#pragma unroll
  for (int ds = 0; ds < 8; ++ds)
    qh[ds] = *(const half8*)(QT + (size_t)qrow * D + ds * 16 + hi * 8);

  f32x16 Ot[4];
#pragma unroll
  for (int dt = 0; dt < 4; ++dt)
#pragma unroll
    for (int e = 0; e < 16; ++e) Ot[dt][e] = 0.f;
  float mrun = -INFINITY, lrun = 0.f;

  const int kvBase = split * splitLen;
  const int nsteps = splitLen / BKV;   // 16 at nsplit=8
  const int tB = kvBase / BKV;

  // staging: K tile -> Kl[KB], V tile -> Vl[VB]; 32 x 1KB chunks, 4 per wave
#define STAGE(KB, VB, T)                                                      \
  {                                                                           \
    _Pragma("unroll")                                                         \
    for (int j = 0; j < 4; ++j) {                                             \
      int cblk = w * 4 + j;                                                   \
      int cc = cblk & 15;                                                     \
      const _Float16* gp = ((cblk < 16) ? PK : PV) +                          \
                           (size_t)(T) * (BKV * D) + cc * 512 + lane * 8;     \
      _Float16* lp = ((cblk < 16) ? &Kl[KB][0] : &Vl[VB][0]) + cc * 512;      \
      __builtin_amdgcn_global_load_lds(                                       \
          (const __attribute__((address_space(1))) unsigned*)gp,              \
          (__attribute__((address_space(3))) unsigned*)lp, 16, 0, 0);         \
    }                                                                         \
  }

  // QK burst: 16 ds_read + 16 MFMA (two independent 8-chains) into s0/s1
  auto QKX = [&](int kb2, f32x16& s0, f32x16& s1) {
    const _Float16* kb = &Kl[kb2][0] + lane * 8;
#pragma unroll
    for (int e = 0; e < 16; ++e) { s0[e] = 0.f; s1[e] = 0.f; }
    __builtin_amdgcn_s_setprio(1);
#pragma unroll
    for (int ds = 0; ds < 8; ++ds) {
      half8 k0 = *(const half8*)(kb + ds * 512);
      half8 k1 = *(const half8*)(kb + (8 + ds) * 512);
      s0 = __builtin_amdgcn_mfma_f32_32x32x16_f16(k0, qh[ds], s0, 0, 0, 0);
      s1 = __builtin_amdgcn_mfma_f32_32x32x16_f16(k1, qh[ds], s1, 0, 0, 0);
    }
    __builtin_amdgcn_s_setprio(0);
  };

  // softmax (exp2 domain) + pack + PV for S in s0/s1, V in Vl[vb3]
  auto SMPV = [&](f32x16& s0, f32x16& s1, int vb3) {
    float t8[8];
#pragma unroll
    for (int e = 0; e < 8; ++e)
      t8[e] = fmaxf(fmaxf(s0[e], s0[e + 8]), fmaxf(s1[e], s1[e + 8]));
    float mx = fmaxf(fmaxf(fmaxf(t8[0], t8[4]), fmaxf(t8[1], t8[5])),
                     fmaxf(fmaxf(t8[2], t8[6]), fmaxf(t8[3], t8[7])));
    mx = fmaxf(mx, __shfl_xor(mx, 32));
    if (!__all(mx - mrun <= DEFER_THR)) {     // defer-max (T13)
      float mn = fmaxf(mrun, mx);
      float sc = fexp2(mrun - mn);            // first iter: exp2(-inf)=0
      mrun = mn;
      lrun *= sc;
#pragma unroll
      for (int dt = 0; dt < 4; ++dt)
#pragma unroll
        for (int e = 0; e < 16; ++e) Ot[dt][e] *= sc;
    }
#pragma unroll
    for (int e = 0; e < 16; ++e) {
      s0[e] = fexp2(s0[e] - mrun);
      s1[e] = fexp2(s1[e] - mrun);
    }
    float a8[8];
#pragma unroll
    for (int e = 0; e < 8; ++e) a8[e] = (s0[e] + s0[e + 8]) + (s1[e] + s1[e + 8]);
    float lsum = ((a8[0] + a8[4]) + (a8[1] + a8[5])) +
                 ((a8[2] + a8[6]) + (a8[3] + a8[7]));
    lsum += __shfl_xor(lsum, 32);
    lrun += lsum;

    unsigned pk[8];
    half8 pb[4];
    union { unsigned u[4]; half8 v; } pbu;
#pragma unroll
    for (int j = 0; j < 8; ++j) pk[j] = cvtpk_h(s0[2 * j], s0[2 * j + 1]);
    pl32swap(pk[0], pk[2]); pl32swap(pk[1], pk[3]);
    pl32swap(pk[4], pk[6]); pl32swap(pk[5], pk[7]);
    pbu.u[0] = pk[0]; pbu.u[1] = pk[1]; pbu.u[2] = pk[2]; pbu.u[3] = pk[3]; pb[0] = pbu.v;
    pbu.u[0] = pk[4]; pbu.u[1] = pk[5]; pbu.u[2] = pk[6]; pbu.u[3] = pk[7]; pb[1] = pbu.v;
#pragma unroll
    for (int j = 0; j < 8; ++j) pk[j] = cvtpk_h(s1[2 * j], s1[2 * j + 1]);
    pl32swap(pk[0], pk[2]); pl32swap(pk[1], pk[3]);
    pl32swap(pk[4], pk[6]); pl32swap(pk[5], pk[7]);
    pbu.u[0] = pk[0]; pbu.u[1] = pk[1]; pbu.u[2] = pk[2]; pbu.u[3] = pk[3]; pb[2] = pbu.v;
    pbu.u[0] = pk[4]; pbu.u[1] = pk[5]; pbu.u[2] = pk[6]; pbu.u[3] = pk[7]; pb[3] = pbu.v;

    const _Float16* vb = &Vl[vb3][0] + lane * 8;
    __builtin_amdgcn_s_setprio(1);
#pragma unroll
    for (int dt = 0; dt < 4; ++dt) {
      half8 v0 = *(const half8*)(vb + (dt * 4 + 0) * 512);
      half8 v1 = *(const half8*)(vb + (dt * 4 + 1) * 512);
      half8 v2 = *(const half8*)(vb + (dt * 4 + 2) * 512);
      half8 v3 = *(const half8*)(vb + (dt * 4 + 3) * 512);
      Ot[dt] = __builtin_amdgcn_mfma_f32_32x32x16_f16(v0, pb[0], Ot[dt], 0, 0, 0);
      Ot[dt] = __builtin_amdgcn_mfma_f32_32x32x16_f16(v1, pb[1], Ot[dt], 0, 0, 0);
      Ot[dt] = __builtin_amdgcn_mfma_f32_32x32x16_f16(v2, pb[2], Ot[dt], 0, 0, 0);
      Ot[dt] = __builtin_amdgcn_mfma_f32_32x32x16_f16(v3, pb[3], Ot[dt], 0, 0, 0);
    }
    __builtin_amdgcn_s_setprio(0);
  };

  f32x16 sA0, sA1, sB0, sB1;

  // ---- prologue: tile 0 ----
  STAGE(0, 0, tB);
  __syncthreads();
  if (nsteps > 1) STAGE(1, 1, tB + 1);
  QKX(0, sA0, sA1);
  __syncthreads();          // tile 1 landed

  // ---- main: phase p = {QK(tile p), SMPV(tile p-1)}, unrolled by 2 ----
  int p = 1;
  for (; p + 1 < nsteps; p += 2) {
    // phase p (odd): reads K1,V[(p-1)%3]; writes K0,V[(p+1)%3]
    STAGE(0, (p + 1) % 3, tB + p + 1);
    QKX(1, sB0, sB1);
    SMPV(sA0, sA1, (p - 1) % 3);
    __syncthreads();
    // phase p+1 (even): reads K0,V[p%3]; writes K1,V[(p+2)%3]
    if (p + 2 < nsteps) STAGE(1, (p + 2) % 3, tB + p + 2);
    QKX(0, sA0, sA1);
    SMPV(sB0, sB1, p % 3);
    __syncthreads();
  }
  if (p < nsteps) {
    // last odd phase (nsteps even): no staging left
    QKX(1, sB0, sB1);
    SMPV(sA0, sA1, (p - 1) % 3);
    SMPV(sB0, sB1, p % 3);
  } else {
    // nsteps odd: last tile is in sA
    SMPV(sA0, sA1, (nsteps - 1) % 3);
  }

  // ---- epilogue: bf16 partials; d = dt*32 + rg*8 + hi*4 + e ----
  ushort* Op = Opart + (size_t)split * SQ * D + (size_t)qrow * D;
#pragma unroll
  for (int dt = 0; dt < 4; ++dt) {
#pragma unroll
    for (int rg = 0; rg < 4; ++rg) {
      uint2 o2;
      o2.x = cvtpk_bf(Ot[dt][4 * rg + 0], Ot[dt][4 * rg + 1]);
      o2.y = cvtpk_bf(Ot[dt][4 * rg + 2], Ot[dt][4 * rg + 3]);
      *(uint2*)(Op + dt * 32 + rg * 8 + hi * 4) = o2;
    }
  }
  if (hi == 0) {
    Mst[split * SQ + qrow] = mrun;   // log2-domain
    Lst[split * SQ + qrow] = lrun;
  }
}

// 8 outputs per thread: per split one 16B bf16x8 load -> fewer instrs, same BW
__global__ void combine(const ushort* __restrict__ Opart, const float* __restrict__ Mst,
                        const float* __restrict__ Lst, float* __restrict__ out, int nsplit) {
  int t8 = (blockIdx.x * 256 + threadIdx.x) * 8;
  int qi = t8 >> 7;
  float M = -INFINITY;
  for (int s = 0; s < nsplit; ++s) M = fmaxf(M, Mst[s * SQ + qi]);
  float acc[8] = {0.f, 0.f, 0.f, 0.f, 0.f, 0.f, 0.f, 0.f};
  float den = 0.f;
  for (int s = 0; s < nsplit; ++s) {
    float wgt = fexp2(Mst[s * SQ + qi] - M);
    den += wgt * Lst[s * SQ + qi];
    uint4v u = *(const uint4v*)(Opart + (size_t)s * SQ * D + t8);
#pragma unroll
    for (int j = 0; j < 4; ++j) {
      acc[2 * j]     += wgt * bf2f((ushort)(u[j] & 0xffffu));
      acc[2 * j + 1] += wgt * bf2f((ushort)(u[j] >> 16));
    }
  }
  float inv = 1.0f / den;
  f32x4 o0 = { acc[0] * inv, acc[1] * inv, acc[2] * inv, acc[3] * inv };
  f32x4 o1 = { acc[4] * inv, acc[5] * inv, acc[6] * inv, acc[7] * inv };
  *(f32x4*)(out + t8) = o0;
  *(f32x4*)(out + t8 + 4) = o1;
}

extern "C" void kernel_launch(void* const* d_in, const int* in_sizes, int n_in,
                              void* d_out, int out_size, void* d_ws, size_t ws_size,
                              hipStream_t stream) {
  const float* q = (const float*)d_in[0];
  const float* k = (const float*)d_in[1];
  const float* v = (const float*)d_in[2];
  float* out = (float*)d_out;

  char* ws = (char*)d_ws;
  const size_t mat = (size_t)SQ * D * 2;   // 2 MB per f16 matrix
  _Float16* QT = (_Float16*)(ws);
  _Float16* PK = (_Float16*)(ws + mat);
  _Float16* PV = (_Float16*)(ws + 2 * mat);
  char* rest = ws + 3 * mat;

  const size_t opartSz = (size_t)SQ * D * 2;  // bf16 partials: 2 MB per split
  const size_t statSz  = (size_t)SQ * 4;
  int nsplit = 8;    // grid 32 x 8 = 256 blocks = 1 resident 8-wave block/CU
  while (nsplit > 1 &&
         3 * mat + (size_t)nsplit * (opartSz + 2 * statSz) > ws_size) nsplit >>= 1;

  ushort* Opart = (ushort*)rest;
  float* Mst = (float*)(rest + (size_t)nsplit * opartSz);
  float* Lst = (float*)(rest + (size_t)nsplit * opartSz + (size_t)nsplit * statSz);

  prep_all<<<1024, 256, 0, stream>>>(q, k, v, QT, PK, PV);
  flash_fwd<<<dim3(SQ / BQ, nsplit), 512, 0, stream>>>(QT, PK, PV,
                                                       Opart, Mst, Lst, SKV / nsplit);
  combine<<<(SQ * D) / (256 * 8), 256, 0, stream>>>(Opart, Mst, Lst, out, nsplit);
}

// Round 23
// 57.695 us; speedup vs baseline: 3.9975x; 1.0115x over previous
//
#include <hip/hip_runtime.h>
#include <hip/hip_bf16.h>
#include <math.h>

typedef _Float16 half8 __attribute__((ext_vector_type(8)));
typedef __fp16 fp16x2 __attribute__((ext_vector_type(2)));
typedef float f32x4 __attribute__((ext_vector_type(4)));
typedef float f32x16 __attribute__((ext_vector_type(16)));
typedef unsigned uint4v __attribute__((ext_vector_type(4)));

#define D 128
#define SQ 8192
#define SKV 8192
#define BQ 256    // q-rows per block (8 waves x 32)
#define BKV 64
#define LOG2E 1.4426950408889634f
#define DEFER_THR 11.5417f   // 8 * log2(e); P <= 2^11.54 ~ 2981 < f16 max

__device__ __forceinline__ float bf2f(ushort h) {
  union { unsigned u; float f; } v; v.u = ((unsigned)h) << 16;
  return v.f;
}
__device__ __forceinline__ unsigned cvtpk_bf(float a, float b) {
  unsigned r;
  asm("v_cvt_pk_bf16_f32 %0, %1, %2" : "=v"(r) : "v"(a), "v"(b));
  return r;
}
__device__ __forceinline__ unsigned cvtpk_h(float a, float b) {
  union { fp16x2 h; unsigned u; } r;
  r.h = __builtin_amdgcn_cvt_pkrtz(a, b);
  return r.u;
}
__device__ __forceinline__ float fexp2(float x) {
  float r;
  asm("v_exp_f32 %0, %1" : "=v"(r) : "v"(x));
  return r;
}
__device__ __forceinline__ float fmax3(float a, float b, float c) {
  float r;
  asm("v_max3_f32 %0, %1, %2, %3" : "=v"(r) : "v"(a), "v"(b), "v"(c));
  return r;
}
__device__ __forceinline__ void pl32swap(unsigned& a, unsigned& b) {
  asm("v_permlane32_swap_b32 %0, %1" : "+v"(a), "+v"(b));
}

// Merged, vectorized prep (1024 blocks) — unchanged from r16 (validated)
__global__ void prep_all(const float* __restrict__ q, const float* __restrict__ k,
                         const float* __restrict__ v,
                         _Float16* __restrict__ QT, _Float16* __restrict__ PK,
                         _Float16* __restrict__ PV) {
  int b = blockIdx.x;
  int t = threadIdx.x;
  if (b < 512) {
    const bool isQ = (b < 256);
    const float* src = isQ ? q : k;
    const float scl = isQ ? LOG2E : 1.0f;
    int s0 = (isQ ? b : b - 256) * 32;
    __shared__ float lds[128][33];
    int dr = t >> 5, l = t & 31;
#pragma unroll
    for (int j = 0; j < 16; ++j) {
      int dd = dr * 16 + j;
      lds[dd][l] = src[(size_t)dd * SQ + s0 + l];
    }
    __syncthreads();
#pragma unroll
    for (int i = 0; i < 2; ++i) {
      int cid = t + i * 256;        // 0..511
      int c = cid >> 5, sl = cid & 31;
      half8 hv;
#pragma unroll
      for (int e = 0; e < 8; ++e) hv[e] = (_Float16)(lds[c * 8 + e][sl] * scl);
      if (isQ) {
        *(half8*)(QT + (size_t)(s0 + sl) * D + c * 8) = hv;
      } else {
        int srow = s0 + sl;
        size_t elem = (size_t)((srow >> 5) * 8 + (c >> 1)) * 512 +
                      ((c & 1) * 32 + (srow & 31)) * 8;
        *(half8*)(PK + elem) = hv;
      }
    }
  } else {
    int idx = (b - 512) * 256 + t;
    int i8 = idx * 8;
    float4 x0 = *(const float4*)(v + i8);
    float4 x1 = *(const float4*)(v + i8 + 4);
    int drow = i8 >> 13;          // / SKV
    int kv = i8 & (SKV - 1);
    size_t elem = (size_t)(kv >> 6) * 8192 +
                  (size_t)((drow >> 5) * 4 + ((kv >> 4) & 3)) * 512 +
                  (((kv >> 3) & 1) * 32 + (drow & 31)) * 8;
    half8 hv = { (_Float16)x0.x, (_Float16)x0.y, (_Float16)x0.z, (_Float16)x0.w,
                 (_Float16)x1.x, (_Float16)x1.y, (_Float16)x1.z, (_Float16)x1.w };
    *(half8*)(PV + elem) = hv;
  }
}

// r18 flash + two micro-trims: V ds_reads hoisted to SMPV entry (latency hides
// under softmax), v_max3 max-reduce (shorter serial chain feeding exp2).
__global__ __launch_bounds__(512, 2)
void flash_fwd(const _Float16* __restrict__ QT, const _Float16* __restrict__ PK,
               const _Float16* __restrict__ PV,
               ushort* __restrict__ Opart, float* __restrict__ Mst,
               float* __restrict__ Lst, int splitLen) {
  __shared__ _Float16 Kl[2][BKV * D];   // 2 x 16 KB
  __shared__ _Float16 Vl[3][BKV * D];   // 3 x 16 KB

  const int tid = threadIdx.x;
  const int w = tid >> 6;        // 0..7
  const int lane = tid & 63;
  const int lc = lane & 31;
  const int hi = lane >> 5;
  const int qb = blockIdx.x;
  const int split = blockIdx.y;
  const int qrow = qb * BQ + w * 32 + lc;

  // Q B-frags (col = q = lc, k-dim = d), pre-scaled by log2e
  half8 qh[8];
#pragma unroll
  for (int ds = 0; ds < 8; ++ds)
    qh[ds] = *(const half8*)(QT + (size_t)qrow * D + ds * 16 + hi * 8);

  f32x16 Ot[4];
#pragma unroll
  for (int dt = 0; dt < 4; ++dt)
#pragma unroll
    for (int e = 0; e < 16; ++e) Ot[dt][e] = 0.f;
  float mrun = -INFINITY, lrun = 0.f;

  const int kvBase = split * splitLen;
  const int nsteps = splitLen / BKV;   // 16 at nsplit=8
  const int tB = kvBase / BKV;

  // staging: K tile -> Kl[KB], V tile -> Vl[VB]; 32 x 1KB chunks, 4 per wave
#define STAGE(KB, VB, T)                                                      \
  {                                                                           \
    _Pragma("unroll")                                                         \
    for (int j = 0; j < 4; ++j) {                                             \
      int cblk = w * 4 + j;                                                   \
      int cc = cblk & 15;                                                     \
      const _Float16* gp = ((cblk < 16) ? PK : PV) +                          \
                           (size_t)(T) * (BKV * D) + cc * 512 + lane * 8;     \
      _Float16* lp = ((cblk < 16) ? &Kl[KB][0] : &Vl[VB][0]) + cc * 512;      \
      __builtin_amdgcn_global_load_lds(                                       \
          (const __attribute__((address_space(1))) unsigned*)gp,              \
          (__attribute__((address_space(3))) unsigned*)lp, 16, 0, 0);         \
    }                                                                         \
  }

  // QK burst: 16 ds_read + 16 MFMA (two independent 8-chains) into s0/s1
  auto QKX = [&](int kb2, f32x16& s0, f32x16& s1) {
    const _Float16* kb = &Kl[kb2][0] + lane * 8;
#pragma unroll
    for (int e = 0; e < 16; ++e) { s0[e] = 0.f; s1[e] = 0.f; }
    __builtin_amdgcn_s_setprio(1);
#pragma unroll
    for (int ds = 0; ds < 8; ++ds) {
      half8 k0 = *(const half8*)(kb + ds * 512);
      half8 k1 = *(const half8*)(kb + (8 + ds) * 512);
      s0 = __builtin_amdgcn_mfma_f32_32x32x16_f16(k0, qh[ds], s0, 0, 0, 0);
      s1 = __builtin_amdgcn_mfma_f32_32x32x16_f16(k1, qh[ds], s1, 0, 0, 0);
    }
    __builtin_amdgcn_s_setprio(0);
  };

  // softmax (exp2 domain) + pack + PV for S in s0/s1, V in Vl[vb3]
  auto SMPV = [&](f32x16& s0, f32x16& s1, int vb3) {
    // V frags issued FIRST: ~120cyc lgkm latency hides under softmax (~700cyc)
    const _Float16* vb = &Vl[vb3][0] + lane * 8;
    half8 va[16];
#pragma unroll
    for (int f = 0; f < 16; ++f) va[f] = *(const half8*)(vb + f * 512);

    // max reduce via v_max3: 32 -> 11 -> 4 -> 2 -> 1 (shorter chain than fmax tree)
    float m0 = fmax3(s0[0], s0[1], s0[2]);
    float m1 = fmax3(s0[3], s0[4], s0[5]);
    float m2 = fmax3(s0[6], s0[7], s0[8]);
    float m3 = fmax3(s0[9], s0[10], s0[11]);
    float m4 = fmax3(s0[12], s0[13], s0[14]);
    float m5 = fmax3(s0[15], s1[0], s1[1]);
    float m6 = fmax3(s1[2], s1[3], s1[4]);
    float m7 = fmax3(s1[5], s1[6], s1[7]);
    float m8 = fmax3(s1[8], s1[9], s1[10]);
    float m9 = fmax3(s1[11], s1[12], s1[13]);
    float ma = fmaxf(s1[14], s1[15]);
    float n0 = fmax3(m0, m1, m2);
    float n1 = fmax3(m3, m4, m5);
    float n2 = fmax3(m6, m7, m8);
    float n3 = fmaxf(m9, ma);
    float mx = fmaxf(fmax3(n0, n1, n2), n3);
    mx = fmaxf(mx, __shfl_xor(mx, 32));

    if (!__all(mx - mrun <= DEFER_THR)) {     // defer-max (T13)
      float mn = fmaxf(mrun, mx);
      float sc = fexp2(mrun - mn);            // first iter: exp2(-inf)=0
      mrun = mn;
      lrun *= sc;
#pragma unroll
      for (int dt = 0; dt < 4; ++dt)
#pragma unroll
        for (int e = 0; e < 16; ++e) Ot[dt][e] *= sc;
    }
#pragma unroll
    for (int e = 0; e < 16; ++e) {
      s0[e] = fexp2(s0[e] - mrun);
      s1[e] = fexp2(s1[e] - mrun);
    }
    float a8[8];
#pragma unroll
    for (int e = 0; e < 8; ++e) a8[e] = (s0[e] + s0[e + 8]) + (s1[e] + s1[e + 8]);
    float lsum = ((a8[0] + a8[4]) + (a8[1] + a8[5])) +
                 ((a8[2] + a8[6]) + (a8[3] + a8[7]));
    lsum += __shfl_xor(lsum, 32);
    lrun += lsum;

    unsigned pk[8];
    half8 pb[4];
    union { unsigned u[4]; half8 v; } pbu;
#pragma unroll
    for (int j = 0; j < 8; ++j) pk[j] = cvtpk_h(s0[2 * j], s0[2 * j + 1]);
    pl32swap(pk[0], pk[2]); pl32swap(pk[1], pk[3]);
    pl32swap(pk[4], pk[6]); pl32swap(pk[5], pk[7]);
    pbu.u[0] = pk[0]; pbu.u[1] = pk[1]; pbu.u[2] = pk[2]; pbu.u[3] = pk[3]; pb[0] = pbu.v;
    pbu.u[0] = pk[4]; pbu.u[1] = pk[5]; pbu.u[2] = pk[6]; pbu.u[3] = pk[7]; pb[1] = pbu.v;
#pragma unroll
    for (int j = 0; j < 8; ++j) pk[j] = cvtpk_h(s1[2 * j], s1[2 * j + 1]);
    pl32swap(pk[0], pk[2]); pl32swap(pk[1], pk[3]);
    pl32swap(pk[4], pk[6]); pl32swap(pk[5], pk[7]);
    pbu.u[0] = pk[0]; pbu.u[1] = pk[1]; pbu.u[2] = pk[2]; pbu.u[3] = pk[3]; pb[2] = pbu.v;
    pbu.u[0] = pk[4]; pbu.u[1] = pk[5]; pbu.u[2] = pk[6]; pbu.u[3] = pk[7]; pb[3] = pbu.v;

    __builtin_amdgcn_s_setprio(1);
#pragma unroll
    for (int dt = 0; dt < 4; ++dt) {
      Ot[dt] = __builtin_amdgcn_mfma_f32_32x32x16_f16(va[dt * 4 + 0], pb[0], Ot[dt], 0, 0, 0);
      Ot[dt] = __builtin_amdgcn_mfma_f32_32x32x16_f16(va[dt * 4 + 1], pb[1], Ot[dt], 0, 0, 0);
      Ot[dt] = __builtin_amdgcn_mfma_f32_32x32x16_f16(va[dt * 4 + 2], pb[2], Ot[dt], 0, 0, 0);
      Ot[dt] = __builtin_amdgcn_mfma_f32_32x32x16_f16(va[dt * 4 + 3], pb[3], Ot[dt], 0, 0, 0);
    }
    __builtin_amdgcn_s_setprio(0);
  };

  f32x16 sA0, sA1, sB0, sB1;

  // ---- prologue: tile 0 ----
  STAGE(0, 0, tB);
  __syncthreads();
  if (nsteps > 1) STAGE(1, 1, tB + 1);
  QKX(0, sA0, sA1);
  __syncthreads();          // tile 1 landed

  // ---- main: phase p = {QK(tile p), SMPV(tile p-1)}, unrolled by 2 ----
  int p = 1;
  for (; p + 1 < nsteps; p += 2) {
    // phase p (odd): reads K1,V[(p-1)%3]; writes K0,V[(p+1)%3]
    STAGE(0, (p + 1) % 3, tB + p + 1);
    QKX(1, sB0, sB1);
    SMPV(sA0, sA1, (p - 1) % 3);
    __syncthreads();
    // phase p+1 (even): reads K0,V[p%3]; writes K1,V[(p+2)%3]
    if (p + 2 < nsteps) STAGE(1, (p + 2) % 3, tB + p + 2);
    QKX(0, sA0, sA1);
    SMPV(sB0, sB1, p % 3);
    __syncthreads();
  }
  if (p < nsteps) {
    // last odd phase (nsteps even): no staging left
    QKX(1, sB0, sB1);
    SMPV(sA0, sA1, (p - 1) % 3);
    SMPV(sB0, sB1, p % 3);
  } else {
    // nsteps odd: last tile is in sA
    SMPV(sA0, sA1, (nsteps - 1) % 3);
  }

  // ---- epilogue: bf16 partials; d = dt*32 + rg*8 + hi*4 + e ----
  ushort* Op = Opart + (size_t)split * SQ * D + (size_t)qrow * D;
#pragma unroll
  for (int dt = 0; dt < 4; ++dt) {
#pragma unroll
    for (int rg = 0; rg < 4; ++rg) {
      uint2 o2;
      o2.x = cvtpk_bf(Ot[dt][4 * rg + 0], Ot[dt][4 * rg + 1]);
      o2.y = cvtpk_bf(Ot[dt][4 * rg + 2], Ot[dt][4 * rg + 3]);
      *(uint2*)(Op + dt * 32 + rg * 8 + hi * 4) = o2;
    }
  }
  if (hi == 0) {
    Mst[split * SQ + qrow] = mrun;   // log2-domain
    Lst[split * SQ + qrow] = lrun;
  }
}

// 8 outputs per thread: per split one 16B bf16x8 load
__global__ void combine(const ushort* __restrict__ Opart, const float* __restrict__ Mst,
                        const float* __restrict__ Lst, float* __restrict__ out, int nsplit) {
  int t8 = (blockIdx.x * 256 + threadIdx.x) * 8;
  int qi = t8 >> 7;
  float M = -INFINITY;
  for (int s = 0; s < nsplit; ++s) M = fmaxf(M, Mst[s * SQ + qi]);
  float acc[8] = {0.f, 0.f, 0.f, 0.f, 0.f, 0.f, 0.f, 0.f};
  float den = 0.f;
  for (int s = 0; s < nsplit; ++s) {
    float wgt = fexp2(Mst[s * SQ + qi] - M);
    den += wgt * Lst[s * SQ + qi];
    uint4v u = *(const uint4v*)(Opart + (size_t)s * SQ * D + t8);
#pragma unroll
    for (int j = 0; j < 4; ++j) {
      acc[2 * j]     += wgt * bf2f((ushort)(u[j] & 0xffffu));
      acc[2 * j + 1] += wgt * bf2f((ushort)(u[j] >> 16));
    }
  }
  float inv = 1.0f / den;
  f32x4 o0 = { acc[0] * inv, acc[1] * inv, acc[2] * inv, acc[3] * inv };
  f32x4 o1 = { acc[4] * inv, acc[5] * inv, acc[6] * inv, acc[7] * inv };
  *(f32x4*)(out + t8) = o0;
  *(f32x4*)(out + t8 + 4) = o1;
}

extern "C" void kernel_launch(void* const* d_in, const int* in_sizes, int n_in,
                              void* d_out, int out_size, void* d_ws, size_t ws_size,
                              hipStream_t stream) {
  const float* q = (const float*)d_in[0];
  const float* k = (const float*)d_in[1];
  const float* v = (const float*)d_in[2];
  float* out = (float*)d_out;

  char* ws = (char*)d_ws;
  const size_t mat = (size_t)SQ * D * 2;   // 2 MB per f16 matrix
  _Float16* QT = (_Float16*)(ws);
  _Float16* PK = (_Float16*)(ws + mat);
  _Float16* PV = (_Float16*)(ws + 2 * mat);
  char* rest = ws + 3 * mat;

  const size_t opartSz = (size_t)SQ * D * 2;  // bf16 partials: 2 MB per split
  const size_t statSz  = (size_t)SQ * 4;
  int nsplit = 8;    // grid 32 x 8 = 256 blocks = 1 resident 8-wave block/CU
  while (nsplit > 1 &&
         3 * mat + (size_t)nsplit * (opartSz + 2 * statSz) > ws_size) nsplit >>= 1;

  ushort* Opart = (ushort*)rest;
  float* Mst = (float*)(rest + (size_t)nsplit * opartSz);
  float* Lst = (float*)(rest + (size_t)nsplit * opartSz + (size_t)nsplit * statSz);

  prep_all<<<1024, 256, 0, stream>>>(q, k, v, QT, PK, PV);
  flash_fwd<<<dim3(SQ / BQ, nsplit), 512, 0, stream>>>(QT, PK, PV,
                                                       Opart, Mst, Lst, SKV / nsplit);
  combine<<<(SQ * D) / (256 * 8), 256, 0, stream>>>(Opart, Mst, Lst, out, nsplit);
}